// Round 2
// baseline (32.166 us; speedup 1.0000x reference)
//
#include <hip/hip_runtime.h>
#include <math.h>

#define PATCH 512
#define SLACK 64
#define STEP  (PATCH - SLACK)   /* 448 */
#define HS    (SLACK / 2)       /* 32  */

struct Geom {
    int p0, p1;     // patch top-left in image
    int gi0, gi1;   // paste dest top-left in image
    int ph, pw;     // paste height/width
};

// All geometry from make_grid + paste_coords, derived from uniform scalar i.
__device__ __forceinline__ Geom compute_geom(int i, int H, int W) {
    const int gh = (H - PATCH + STEP - 1) / STEP + 1;
    const int gw = (W - PATCH + STEP - 1) / STEP + 1;
    const int r = i / gw;
    const int c = i % gw;
    const int gyr = min(PATCH + r * STEP, H);
    const int gxc = min(PATCH + c * STEP, W);
    Geom g;
    g.p0 = max(gyr - PATCH, 0);
    g.p1 = max(gxc - PATCH, 0);
    const int gy_m2 = min(PATCH + (gh - 2) * STEP, H);
    const int gx_m2 = min(PATCH + (gw - 2) * STEP, W);
    const int gy_m1 = min(PATCH + (gh - 1) * STEP, H);
    const int gx_m1 = min(PATCH + (gw - 1) * STEP, W);
    const int lh0 = (gy_m2 - (gy_m1 - PATCH)) / 2;
    const int lh1 = (gx_m2 - (gx_m1 - PATCH)) / 2;
    const int di0 = (r == 0) ? 0 : ((r == gh - 1) ? lh0 : HS);
    const int di1 = (c == 0) ? 0 : ((c == gw - 1) ? lh1 : HS);
    const int di2 = (r < gh - 1) ? (PATCH - HS) : PATCH;
    const int di3 = (c < gw - 1) ? (PATCH - HS) : PATCH;
    g.gi0 = g.p0 + di0;
    g.gi1 = g.p1 + di1;
    g.ph  = di2 - di0;
    g.pw  = di3 - di1;
    return g;
}

// conv3x3 + bias + sigmoid at patch coords (py,px); zero-pad at patch border.
__device__ __forceinline__ float conv_px(const int* __restrict__ x,
                                         const float* __restrict__ Wt,
                                         float bias, int py, int px,
                                         int p0, int p1, int W) {
    const float inv255 = 1.0f / 255.0f;
    float acc = bias;
#pragma unroll
    for (int ky = 0; ky < 3; ++ky) {
        const int ppy = py + ky - 1;
        if (ppy < 0 || ppy >= PATCH) continue;
        const int ih = p0 + ppy;
#pragma unroll
        for (int kx = 0; kx < 3; ++kx) {
            const int ppx = px + kx - 1;
            if (ppx < 0 || ppx >= PATCH) continue;
            const int iw = p1 + ppx;
            const int* __restrict__ xp = x + ((size_t)ih * W + iw) * 3;
            acc += Wt[0 * 9 + ky * 3 + kx] * ((float)xp[0] * inv255)
                 + Wt[1 * 9 + ky * 3 + kx] * ((float)xp[1] * inv255)
                 + Wt[2 * 9 + ky * 3 + kx] * ((float)xp[2] * inv255);
        }
    }
    return 1.0f / (1.0f + expf(-acc));
}

// ---------------------------------------------------------------------------
// Fused: out = (i>0 ? y : 0) with the conv+sigmoid patch pasted over
// [gi0:gi0+ph, gi1:gi1+pw]. One float4 of the output row per thread.
// Grid: (ceil((W/4)/256), H) — no integer division on the hot path.
// ---------------------------------------------------------------------------
__global__ __launch_bounds__(256) void fused_kernel(
        const int* __restrict__ x, const float* __restrict__ y,
        const float* __restrict__ Wt, const float* __restrict__ bp,
        const int* __restrict__ ip, float* __restrict__ out,
        int H, int W) {
    const int w4 = W >> 2;
    const int row = blockIdx.y;
    const int q = blockIdx.x * blockDim.x + threadIdx.x;  // float4 index in row
    if (q >= w4) return;
    const int c0 = q << 2;                                // first pixel column
    const int i = *ip;                                    // uniform scalar
    const Geom g = compute_geom(i, H, W);

    const size_t idx = (size_t)row * w4 + q;
    float4 v;
    const bool rowin = (row >= g.gi0) && (row < g.gi0 + g.ph);
    if (!rowin || (c0 + 3 < g.gi1) || (c0 >= g.gi1 + g.pw)) {
        // pure base-plane path
        v = (i > 0) ? ((const float4*)y)[idx]
                    : make_float4(0.f, 0.f, 0.f, 0.f);
    } else {
        const float bias = *bp;
        float vv[4];
#pragma unroll
        for (int j = 0; j < 4; ++j) {
            const int col = c0 + j;
            if (col >= g.gi1 && col < g.gi1 + g.pw) {
                vv[j] = conv_px(x, Wt, bias, row - g.p0, col - g.p1,
                                g.p0, g.p1, W);
            } else {
                vv[j] = (i > 0) ? y[(size_t)row * W + col] : 0.f;
            }
        }
        v = make_float4(vv[0], vv[1], vv[2], vv[3]);
    }
    ((float4*)out)[idx] = v;
}

// ---------------------------------------------------------------------------
extern "C" void kernel_launch(void* const* d_in, const int* in_sizes, int n_in,
                              void* d_out, int out_size, void* d_ws, size_t ws_size,
                              hipStream_t stream) {
    const int*   x  = (const int*)d_in[0];    // (1,H,W,3) int32
    const float* y  = (const float*)d_in[1];  // (1,1,H,W) f32
    const float* Wt = (const float*)d_in[2];  // (1,3,3,3) f32
    const float* b  = (const float*)d_in[3];  // (1,) f32
    const int*   ip = (const int*)d_in[4];    // scalar i
    float* out = (float*)d_out;

    // square plane: H = W = sqrt(out_size)
    int H = 1;
    while ((long long)(H + 1) * (H + 1) <= (long long)out_size) ++H;
    const int Wd = H;

    const int w4 = Wd >> 2;
    dim3 blk(256, 1);
    dim3 grd((w4 + 255) / 256, H);
    fused_kernel<<<grd, blk, 0, stream>>>(x, y, Wt, b, ip, out, H, Wd);
}

// Round 3
// 31.715 us; speedup vs baseline: 1.0142x; 1.0142x over previous
//
#include <hip/hip_runtime.h>
#include <math.h>

#define PATCH 512
#define SLACK 64
#define STEP  (PATCH - SLACK)   /* 448 */
#define HS    (SLACK / 2)       /* 32  */

struct Geom {
    int p0, p1;     // patch top-left in image
    int gi0, gi1;   // paste dest top-left in image
    int ph, pw;     // paste height/width
};

// All geometry from make_grid + paste_coords. `i` is an SGPR value, so this
// whole function compiles to SALU (one scalar unit op stream per wave).
__device__ __forceinline__ Geom compute_geom(int i, int H, int W) {
    const int gh = (H - PATCH + STEP - 1) / STEP + 1;
    const int gw = (W - PATCH + STEP - 1) / STEP + 1;
    const int r = (unsigned)i / (unsigned)gw;
    const int c = (unsigned)i % (unsigned)gw;
    const int gyr = min(PATCH + r * STEP, H);
    const int gxc = min(PATCH + c * STEP, W);
    Geom g;
    g.p0 = max(gyr - PATCH, 0);
    g.p1 = max(gxc - PATCH, 0);
    const int gy_m2 = min(PATCH + (gh - 2) * STEP, H);
    const int gx_m2 = min(PATCH + (gw - 2) * STEP, W);
    const int gy_m1 = min(PATCH + (gh - 1) * STEP, H);
    const int gx_m1 = min(PATCH + (gw - 1) * STEP, W);
    const int lh0 = (gy_m2 - (gy_m1 - PATCH)) / 2;
    const int lh1 = (gx_m2 - (gx_m1 - PATCH)) / 2;
    const int di0 = (r == 0) ? 0 : ((r == gh - 1) ? lh0 : HS);
    const int di1 = (c == 0) ? 0 : ((c == gw - 1) ? lh1 : HS);
    const int di2 = (r < gh - 1) ? (PATCH - HS) : PATCH;
    const int di3 = (c < gw - 1) ? (PATCH - HS) : PATCH;
    g.gi0 = g.p0 + di0;
    g.gi1 = g.p1 + di1;
    g.ph  = di2 - di0;
    g.pw  = di3 - di1;
    return g;
}

// conv3x3 + bias + sigmoid at patch coords (py,px); zero-pad at patch border.
__device__ __forceinline__ float conv_px(const int* __restrict__ x,
                                         const float* __restrict__ Wt,
                                         float bias, int py, int px,
                                         int p0, int p1, int W) {
    const float inv255 = 1.0f / 255.0f;
    float acc = bias;
#pragma unroll
    for (int ky = 0; ky < 3; ++ky) {
        const int ppy = py + ky - 1;
        if (ppy < 0 || ppy >= PATCH) continue;
        const int ih = p0 + ppy;
#pragma unroll
        for (int kx = 0; kx < 3; ++kx) {
            const int ppx = px + kx - 1;
            if (ppx < 0 || ppx >= PATCH) continue;
            const int iw = p1 + ppx;
            const int* __restrict__ xp = x + ((size_t)ih * W + iw) * 3;
            acc += Wt[0 * 9 + ky * 3 + kx] * ((float)xp[0] * inv255)
                 + Wt[1 * 9 + ky * 3 + kx] * ((float)xp[1] * inv255)
                 + Wt[2 * 9 + ky * 3 + kx] * ((float)xp[2] * inv255);
        }
    }
    return 1.0f / (1.0f + expf(-acc));
}

// ---------------------------------------------------------------------------
// One block per output row. Geometry is scalar (SALU); the row-vs-rect test
// is one uniform branch per block. Fast path: pure float4 copy / zero-fill,
// 4 iterations per thread. Only rect-intersecting rows (ph of H) take the
// per-element path.
// ---------------------------------------------------------------------------
__global__ __launch_bounds__(256) void fused_kernel(
        const int* __restrict__ x, const float* __restrict__ y,
        const float* __restrict__ Wt, const float* __restrict__ bp,
        const int* __restrict__ ip, float* __restrict__ out,
        int H, int W) {
    const int row = blockIdx.x;
    const int t = threadIdx.x;
    const int i = __builtin_amdgcn_readfirstlane(ip[0]);  // uniform -> SGPR
    const Geom g = compute_geom(i, H, W);                 // SALU
    const int w4 = W >> 2;
    const size_t rowbase = (size_t)row * w4;
    const float4* __restrict__ y4 = (const float4*)y;
    float4* __restrict__ o4 = (float4*)out;

    const bool rowin = (row >= g.gi0) && (row < g.gi0 + g.ph);  // scalar
    if (!rowin) {
        if (i > 0) {
            for (int q = t; q < w4; q += 256)
                o4[rowbase + q] = y4[rowbase + q];
        } else {
            const float4 z = make_float4(0.f, 0.f, 0.f, 0.f);
            for (int q = t; q < w4; q += 256)
                o4[rowbase + q] = z;
        }
        return;
    }

    // row intersects the paste rectangle
    const float bias = bp[0];
    const int cl = g.gi1, cr = g.gi1 + g.pw;   // [cl, cr) = rect columns
    for (int q = t; q < w4; q += 256) {
        const int c0 = q << 2;
        float4 v;
        if (c0 + 3 < cl || c0 >= cr) {
            v = (i > 0) ? y4[rowbase + q] : make_float4(0.f, 0.f, 0.f, 0.f);
        } else {
            float vv[4];
#pragma unroll
            for (int j = 0; j < 4; ++j) {
                const int col = c0 + j;
                if (col >= cl && col < cr) {
                    vv[j] = conv_px(x, Wt, bias, row - g.p0, col - g.p1,
                                    g.p0, g.p1, W);
                } else {
                    vv[j] = (i > 0) ? y[(size_t)row * W + col] : 0.f;
                }
            }
            v = make_float4(vv[0], vv[1], vv[2], vv[3]);
        }
        o4[rowbase + q] = v;
    }
}

// ---------------------------------------------------------------------------
extern "C" void kernel_launch(void* const* d_in, const int* in_sizes, int n_in,
                              void* d_out, int out_size, void* d_ws, size_t ws_size,
                              hipStream_t stream) {
    const int*   x  = (const int*)d_in[0];    // (1,H,W,3) int32
    const float* y  = (const float*)d_in[1];  // (1,1,H,W) f32
    const float* Wt = (const float*)d_in[2];  // (1,3,3,3) f32
    const float* b  = (const float*)d_in[3];  // (1,) f32
    const int*   ip = (const int*)d_in[4];    // scalar i
    float* out = (float*)d_out;

    // square plane: H = W = sqrt(out_size)
    int H = 1;
    while ((long long)(H + 1) * (H + 1) <= (long long)out_size) ++H;
    const int Wd = H;

    fused_kernel<<<dim3(H), dim3(256), 0, stream>>>(x, y, Wt, b, ip, out, H, Wd);
}